// Round 2
// baseline (13853.703 us; speedup 1.0000x reference)
//
#include <hip/hip_runtime.h>
#include <hip/hip_bf16.h>

// Problem constants (from reference)
#define NPTS    16384
#define IN_DIM  64
#define HID     128
#define ODIM    128
#define KSEL    32

#define CAP     256   // per-row candidate buffer slots
#define POSINF  __int_as_float(0x7f800000)

// ---------------------------------------------------------------------------
// Kernel A: row squared norms. 16384 threads, one row each.
// ---------------------------------------------------------------------------
__global__ __launch_bounds__(256) void sqnorm_kernel(const float* __restrict__ x,
                                                     float* __restrict__ sq) {
    int i = blockIdx.x * 256 + threadIdx.x;
    const float4* xr = (const float4*)(x + (size_t)i * IN_DIM);
    float s = 0.f;
#pragma unroll
    for (int q = 0; q < 16; ++q) {
        float4 v = xr[q];
        s += v.x * v.x + v.y * v.y + v.z * v.z + v.w * v.w;
    }
    sq[i] = s;
}

// ---------------------------------------------------------------------------
// Kernel B: fused distance GEMM (fp32) + streaming top-32 selection.
// Block: 256 threads (4 waves), 64 rows. Grid: 256 blocks (= #CUs).
// Tile: 64 rows x 128 cols, K=64. Micro: 4x8 per lane (rows/cols strided by 8).
// Selection: threshold filter -> LDS buffer -> bisect-compact -> exact extract.
// ---------------------------------------------------------------------------
__global__ __launch_bounds__(256, 1) void knn_kernel(const float* __restrict__ x,
                                                     const float* __restrict__ sq,
                                                     int* __restrict__ graph) {
    __shared__ float As[64][72];          // 18.4 KB (pad 72: 2-way bank alias only)
    __shared__ float Bs[128][72];         // 36.9 KB
    __shared__ float sA[64];
    __shared__ float sB[128];
    __shared__ float bd[64][CAP];         // 64 KB candidate distances (>=0)
    __shared__ unsigned short bj[64][CAP];// 32 KB candidate indices
    __shared__ int   bcnt[64];
    __shared__ float bthr[64];

    const int t      = threadIdx.x;
    const int lane   = t & 63;
    const int wave   = t >> 6;
    const int lane_r = lane >> 3;   // 0..7
    const int lane_c = lane & 7;    // 0..7
    const int waveR  = wave >> 1;   // 0..1  (rows half)
    const int waveC  = wave & 1;    // 0..1  (cols half)
    const int rbase  = blockIdx.x * 64;

    // Stage A tile (64 rows x 64 K) once; init selection state.
    for (int idx = t; idx < 64 * 16; idx += 256) {
        int r = idx >> 4, q = idx & 15;
        float4 v = ((const float4*)(x + (size_t)(rbase + r) * IN_DIM))[q];
        *(float4*)&As[r][q * 4] = v;
    }
    if (t < 64) { sA[t] = sq[rbase + t]; bcnt[t] = 0; bthr[t] = POSINF; }
    __syncthreads();

    for (int tile = 0; tile < NPTS / 128; ++tile) {
        const int cb = tile * 128;
        // Stage B tile (128 rows x 64 K) + sqB
        for (int idx = t; idx < 128 * 16; idx += 256) {
            int r = idx >> 4, q = idx & 15;
            float4 v = ((const float4*)(x + (size_t)(cb + r) * IN_DIM))[q];
            *(float4*)&Bs[r][q * 4] = v;
        }
        if (t < 128) sB[t] = sq[cb + t];
        __syncthreads();

        // GEMM core: acc[i][m] = dot64(row, col)
        float acc[4][8];
#pragma unroll
        for (int i = 0; i < 4; ++i)
#pragma unroll
            for (int m = 0; m < 8; ++m) acc[i][m] = 0.f;

#pragma unroll
        for (int q = 0; q < 16; ++q) {
            float4 a[4], b[8];
#pragma unroll
            for (int i = 0; i < 4; ++i)
                a[i] = *(const float4*)&As[waveR * 32 + i * 8 + lane_r][q * 4];
#pragma unroll
            for (int m = 0; m < 8; ++m)
                b[m] = *(const float4*)&Bs[waveC * 64 + m * 8 + lane_c][q * 4];
#pragma unroll
            for (int i = 0; i < 4; ++i)
#pragma unroll
                for (int m = 0; m < 8; ++m)
                    acc[i][m] += a[i].x * b[m].x + a[i].y * b[m].y +
                                 a[i].z * b[m].z + a[i].w * b[m].w;
        }

        // Epilogue: d2 = sqA + sqB - 2*dot ; threshold filter -> buffer
#pragma unroll
        for (int i = 0; i < 4; ++i) {
            int r = waveR * 32 + i * 8 + lane_r;
            float sar = sA[r];
            float thr = bthr[r];
#pragma unroll
            for (int m = 0; m < 8; ++m) {
                int c = waveC * 64 + m * 8 + lane_c;
                float d = fmaf(-2.f, acc[i][m], sar + sB[c]);
                if (d <= thr) {
                    int pos = atomicAdd(&bcnt[r], 1);
                    if (pos < CAP) {
                        bd[r][pos] = fmaxf(d, 0.f);   // clamp -> monotone float bits
                        bj[r][pos] = (unsigned short)(cb + c);
                    }
                }
            }
        }
        __syncthreads();

        // Compaction: each wave owns rows (wave mod 4). Trigger: cnt > 128 so
        // next tile's <=128 inserts always fit in CAP=256.
        for (int rr = wave; rr < 64; rr += 4) {
            int n = bcnt[rr];
            if (n <= 128) continue;            // wave-uniform branch
            if (n > CAP) n = CAP;
            float dv[4]; unsigned short jv[4];
#pragma unroll
            for (int s = 0; s < 4; ++s) {
                int idxs = lane + s * 64;
                bool v = idxs < n;
                dv[s] = v ? bd[rr][idxs] : POSINF;
                jv[s] = v ? bj[rr][idxs] : 0;
            }
            // bisect float-bit threshold to rank window [32, 96]
            unsigned int lo = 0u, hi = __float_as_uint(bthr[rr]);
            unsigned int ans = hi;
            for (int it = 0; it < 24 && lo < hi; ++it) {
                unsigned int mid = lo + ((hi - lo) >> 1);
                int c = 0;
#pragma unroll
                for (int s = 0; s < 4; ++s)
                    c += __popcll(__ballot(__float_as_uint(dv[s]) <= mid));
                if (c < 32) lo = mid + 1;
                else { hi = mid; ans = mid; if (c <= 96) break; }
            }
            // ballot-scan compaction of kept (<= ans) elements
            int base = 0;
#pragma unroll
            for (int s = 0; s < 4; ++s) {
                bool p = __float_as_uint(dv[s]) <= ans;
                unsigned long long bal = __ballot(p);
                int pos = base + __popcll(bal & ((1ull << lane) - 1ull));
                if (p) { bd[rr][pos] = dv[s]; bj[rr][pos] = jv[s]; }
                base += __popcll(bal);
            }
            if (lane == 0) { bcnt[rr] = base; bthr[rr] = __uint_as_float(ans); }
        }
        __syncthreads();
    }

    // Final exact top-32 per row: packed key (dist_bits<<32)|j, ties -> lower j
    for (int rr = wave; rr < 64; rr += 4) {
        int n = bcnt[rr]; if (n > CAP) n = CAP;
        unsigned long long k[4];
#pragma unroll
        for (int s = 0; s < 4; ++s) {
            int idxs = lane + s * 64;
            if (idxs < n)
                k[s] = ((unsigned long long)__float_as_uint(bd[rr][idxs]) << 32) |
                       (unsigned long long)bj[rr][idxs];
            else
                k[s] = ~0ull;
        }
        int* grow = graph + (size_t)(rbase + rr) * KSEL;
        for (int it = 0; it < KSEL; ++it) {
            unsigned long long m01 = k[0] < k[1] ? k[0] : k[1];
            unsigned long long m23 = k[2] < k[3] ? k[2] : k[3];
            unsigned long long m = m01 < m23 ? m01 : m23;
#pragma unroll
            for (int off = 32; off > 0; off >>= 1) {
                unsigned long long o = __shfl_xor(m, off);
                m = m < o ? m : o;
            }
            if (lane == 0) grow[it] = (int)(m & 0xffffffffull);
#pragma unroll
            for (int s = 0; s < 4; ++s) if (k[s] == m) k[s] = ~0ull;
        }
    }
}

// ---------------------------------------------------------------------------
// Kernel C: XWa[i][h]=x_i . w[h][0:64], XWb[i][h]=x_i . w[h][64:128],
//           OUTB[i][o]=x_i . w2[o][128:192]  (written directly to d_out).
// Block: 384 threads (one weight-slot each, weights in registers), 64 rows.
// ---------------------------------------------------------------------------
__global__ __launch_bounds__(384) void xw_kernel(const float* __restrict__ x,
                                                 const float* __restrict__ w,
                                                 const float* __restrict__ w2,
                                                 float* __restrict__ XWa,
                                                 float* __restrict__ XWb,
                                                 float* __restrict__ outb) {
    __shared__ float xs[64][64];
    const int t = threadIdx.x;
    const int rbase = blockIdx.x * 64;

    for (int idx = t; idx < 64 * 16; idx += 384) {
        int r = idx >> 4, q = idx & 15;
        ((float4*)xs[r])[q] = ((const float4*)(x + (size_t)(rbase + r) * IN_DIM))[q];
    }
    const int kind = t >> 7;       // 0:XWa 1:XWb 2:OUTB
    const int idx  = t & 127;
    const float* wp = (kind == 0) ? (w + (size_t)idx * 128)
                    : (kind == 1) ? (w + (size_t)idx * 128 + 64)
                                  : (w2 + (size_t)idx * 192 + 128);
    float4 wreg[16];
#pragma unroll
    for (int q = 0; q < 16; ++q) wreg[q] = ((const float4*)wp)[q];
    __syncthreads();

    for (int r = 0; r < 64; ++r) {
        float acc = 0.f;
#pragma unroll
        for (int q = 0; q < 16; ++q) {
            float4 xv = ((float4*)xs[r])[q];
            acc += xv.x * wreg[q].x + xv.y * wreg[q].y +
                   xv.z * wreg[q].z + xv.w * wreg[q].w;
        }
        size_t o = (size_t)(rbase + r) * 128 + idx;
        if (kind == 0)      XWa[o]  = acc;
        else if (kind == 1) XWb[o]  = acc;
        else                outb[o] = acc;
    }
}

// ---------------------------------------------------------------------------
// Kernel D: pooled[i][h] = mean_c clip(XWa[g[i][c]][h] + XWb[i][h], -1, 1)
// Block: 256 threads, 8 rows sequentially. Gathers are 512B coalesced rows.
// ---------------------------------------------------------------------------
__global__ __launch_bounds__(256) void pool_kernel(const int* __restrict__ graph,
                                                   const float* __restrict__ XWa,
                                                   const float* __restrict__ XWb,
                                                   float* __restrict__ pooled) {
    __shared__ float xwb[128];
    __shared__ int   gi[KSEL];
    __shared__ float part[256];
    const int t = threadIdx.x;
    const int rbase = blockIdx.x * 8;

    for (int rr = 0; rr < 8; ++rr) {
        int row = rbase + rr;
        if (t < KSEL) gi[t] = graph[(size_t)row * KSEL + t];
        if (t >= 64 && t < 192) xwb[t - 64] = XWb[(size_t)row * 128 + (t - 64)];
        __syncthreads();
        int h = t & 127, grp = t >> 7;
        float b = xwb[h];
        float acc = 0.f;
#pragma unroll
        for (int c = 0; c < 16; ++c) {
            int j = gi[grp * 16 + c];
            float v = XWa[(size_t)j * 128 + h] + b;
            acc += fminf(fmaxf(v, -1.f), 1.f);
        }
        part[t] = acc;
        __syncthreads();
        if (t < 128)
            pooled[(size_t)row * 128 + t] = (part[t] + part[t + 128]) * (1.f / 32.f);
        __syncthreads();
    }
}

// ---------------------------------------------------------------------------
// Kernel E: out[i][o] += pooled[i] . w2[o][0:128]   (out already holds OUTB)
// Block: 256 threads = 128 outs x 2 rows-in-flight; 64 rows per block.
// ---------------------------------------------------------------------------
__global__ __launch_bounds__(256) void out_kernel(const float* __restrict__ pooled,
                                                  const float* __restrict__ w2,
                                                  float* __restrict__ out) {
    __shared__ float ws2[128][132];   // pad 132 -> f4-aligned, banks spread
    __shared__ float pt[64][128];
    const int t = threadIdx.x;
    const int rbase = blockIdx.x * 64;

    for (int idx = t; idx < 128 * 32; idx += 256) {
        int o = idx >> 5, q = idx & 31;
        ((float4*)&ws2[o][0])[q] = ((const float4*)(w2 + (size_t)o * 192))[q];
    }
    for (int idx = t; idx < 64 * 32; idx += 256) {
        int r = idx >> 5, q = idx & 31;
        ((float4*)&pt[r][0])[q] = ((const float4*)(pooled + (size_t)(rbase + r) * 128))[q];
    }
    __syncthreads();

    const int o = t & 127, rsub = t >> 7;
    for (int rp = 0; rp < 32; ++rp) {
        int r = rp * 2 + rsub;
        float acc = 0.f;
#pragma unroll
        for (int q = 0; q < 32; ++q) {
            float4 pv = ((float4*)&pt[r][0])[q];
            float4 wv = ((float4*)&ws2[o][0])[q];
            acc += pv.x * wv.x + pv.y * wv.y + pv.z * wv.z + pv.w * wv.w;
        }
        size_t off = (size_t)(rbase + r) * 128 + o;
        out[off] += acc;
    }
}

// ---------------------------------------------------------------------------
extern "C" void kernel_launch(void* const* d_in, const int* in_sizes, int n_in,
                              void* d_out, int out_size, void* d_ws, size_t ws_size,
                              hipStream_t stream) {
    const float* x  = (const float*)d_in[0];   // (16384, 64)
    const float* w  = (const float*)d_in[1];   // (128, 128)
    const float* w2 = (const float*)d_in[2];   // (128, 192)
    float* out = (float*)d_out;                // (16384, 128)

    // workspace layout (all 16B-aligned)
    float* sq     = (float*)d_ws;                         // 16384 f
    int*   graph  = (int*)(sq + NPTS);                    // 16384*32 i
    float* XWa    = (float*)(graph + (size_t)NPTS * KSEL);// 16384*128 f
    float* XWb    = XWa + (size_t)NPTS * 128;             // 16384*128 f
    float* pooled = XWb + (size_t)NPTS * 128;             // 16384*128 f

    sqnorm_kernel<<<NPTS / 256, 256, 0, stream>>>(x, sq);
    knn_kernel<<<NPTS / 64, 256, 0, stream>>>(x, sq, graph);
    xw_kernel<<<NPTS / 64, 384, 0, stream>>>(x, w, w2, XWa, XWb, out);
    pool_kernel<<<NPTS / 8, 256, 0, stream>>>(graph, XWa, XWb, pooled);
    out_kernel<<<NPTS / 64, 256, 0, stream>>>(pooled, w2, out);
}

// Round 3
// 1771.824 us; speedup vs baseline: 7.8189x; 7.8189x over previous
//
#include <hip/hip_runtime.h>
#include <hip/hip_bf16.h>

// Problem constants (from reference)
#define NPTS    16384
#define IN_DIM  64
#define HID     128
#define ODIM    128
#define KSEL    32

#define CAP     128   // per-row candidate buffer slots
#define POSINF  __int_as_float(0x7f800000)

// ---------------------------------------------------------------------------
// Kernel A: row squared norms. 16384 threads, one row each.
// ---------------------------------------------------------------------------
__global__ __launch_bounds__(256) void sqnorm_kernel(const float* __restrict__ x,
                                                     float* __restrict__ sq) {
    int i = blockIdx.x * 256 + threadIdx.x;
    const float4* xr = (const float4*)(x + (size_t)i * IN_DIM);
    float s = 0.f;
#pragma unroll
    for (int q = 0; q < 16; ++q) {
        float4 v = xr[q];
        s += v.x * v.x + v.y * v.y + v.z * v.z + v.w * v.w;
    }
    sq[i] = s;
}

// ---------------------------------------------------------------------------
// Kernel B: fused distance GEMM (fp32) + streaming top-32 selection.
// Block: 512 threads (8 waves), 64 rows. Grid: 256 blocks (= #CUs).
// Tile: 64 rows x 256 cols, K=64. Micro: 4x8 per lane.
//   waveR = wave>>2 (rows half), waveC = wave&3 (64-col chunk).
// Epilogue serialized over waveC chunks so CAP=128 suffices:
//   enter chunk <=48 (post-compact) -> +64 inserts <= 112 <= CAP.
// unroll 2 on the K loop: prevents the round-0 spill disaster (VGPR cap 256,
// full unroll hoisted ~768 floats -> 9.4 GB scratch writes/dispatch).
// ---------------------------------------------------------------------------
__global__ __launch_bounds__(512, 2) void knn_kernel(const float* __restrict__ x,
                                                     const float* __restrict__ sq,
                                                     int* __restrict__ graph) {
    __shared__ float As[64][72];          // 18.4 KB (pad 72: 2-way alias, free)
    __shared__ float Bs[256][72];         // 73.7 KB
    __shared__ float sA[64];
    __shared__ float sB[256];
    __shared__ float bd[64][CAP];         // 32 KB candidate distances (>=0)
    __shared__ unsigned short bj[64][CAP];// 16 KB candidate indices
    __shared__ int   bcnt[64];
    __shared__ float bthr[64];

    const int t      = threadIdx.x;
    const int lane   = t & 63;
    const int wave   = t >> 6;      // 0..7
    const int lane_r = lane >> 3;   // 0..7
    const int lane_c = lane & 7;    // 0..7
    const int waveR  = wave >> 2;   // 0..1  (row half)
    const int waveC  = wave & 3;    // 0..3  (64-col chunk)
    const int rbase  = blockIdx.x * 64;

    // Stage A tile (64 rows x 64 K) once; init selection state.
    for (int idx = t; idx < 64 * 16; idx += 512) {
        int r = idx >> 4, q = idx & 15;
        float4 v = ((const float4*)(x + (size_t)(rbase + r) * IN_DIM))[q];
        *(float4*)&As[r][q * 4] = v;
    }
    if (t < 64) { sA[t] = sq[rbase + t]; bcnt[t] = 0; bthr[t] = POSINF; }
    __syncthreads();

    for (int tile = 0; tile < NPTS / 256; ++tile) {
        const int cb = tile * 256;
        // Stage B tile (256 rows x 64 K) + sqB
        for (int idx = t; idx < 256 * 16; idx += 512) {
            int r = idx >> 4, q = idx & 15;
            float4 v = ((const float4*)(x + (size_t)(cb + r) * IN_DIM))[q];
            *(float4*)&Bs[r][q * 4] = v;
        }
        if (t < 256) sB[t] = sq[cb + t];
        __syncthreads();

        // GEMM core: acc[i][m] = dot64(row, col). unroll 2 caps live regs.
        float acc[4][8];
#pragma unroll
        for (int i = 0; i < 4; ++i)
#pragma unroll
            for (int m = 0; m < 8; ++m) acc[i][m] = 0.f;

#pragma unroll 2
        for (int q = 0; q < 16; ++q) {
            float4 a[4], b[8];
#pragma unroll
            for (int i = 0; i < 4; ++i)
                a[i] = *(const float4*)&As[waveR * 32 + i * 8 + lane_r][q * 4];
#pragma unroll
            for (int m = 0; m < 8; ++m)
                b[m] = *(const float4*)&Bs[waveC * 64 + m * 8 + lane_c][q * 4];
#pragma unroll
            for (int i = 0; i < 4; ++i)
#pragma unroll
                for (int m = 0; m < 8; ++m)
                    acc[i][m] += a[i].x * b[m].x + a[i].y * b[m].y +
                                 a[i].z * b[m].z + a[i].w * b[m].w;
        }

        // Epilogue: 4 serialized column chunks (chunk == waveC owner).
        for (int chunk = 0; chunk < 4; ++chunk) {
            if (waveC == chunk) {
#pragma unroll
                for (int i = 0; i < 4; ++i) {
                    int r = waveR * 32 + i * 8 + lane_r;
                    float sar = sA[r];
                    float thr = bthr[r];
#pragma unroll
                    for (int m = 0; m < 8; ++m) {
                        int c = waveC * 64 + m * 8 + lane_c;
                        float d = fmaf(-2.f, acc[i][m], sar + sB[c]);
                        if (d <= thr) {
                            int pos = atomicAdd(&bcnt[r], 1);
                            if (pos < CAP) {
                                bd[r][pos] = fmaxf(d, 0.f);  // clamp: monotone bits
                                bj[r][pos] = (unsigned short)(cb + c);
                            }
                        }
                    }
                }
            }
            __syncthreads();

            // Compaction: rows strided over 8 waves. Trigger cnt > 64 so the
            // next chunk's <=64 inserts always fit in CAP=128.
            for (int rr = wave; rr < 64; rr += 8) {
                int n = bcnt[rr];
                if (n <= 64) continue;            // wave-uniform branch
                if (n > CAP) n = CAP;
                float dv[2]; unsigned short jv[2];
#pragma unroll
                for (int s = 0; s < 2; ++s) {
                    int idxs = lane + s * 64;
                    bool v = idxs < n;
                    dv[s] = v ? bd[rr][idxs] : POSINF;
                    jv[s] = v ? bj[rr][idxs] : 0;
                }
                // bisect float-bit threshold to rank window [32, 48]
                unsigned int lo = 0u, hi = __float_as_uint(bthr[rr]);
                unsigned int ans = hi;
                for (int it = 0; it < 26 && lo < hi; ++it) {
                    unsigned int mid = lo + ((hi - lo) >> 1);
                    int c = 0;
#pragma unroll
                    for (int s = 0; s < 2; ++s)
                        c += __popcll(__ballot(__float_as_uint(dv[s]) <= mid));
                    if (c < 32) lo = mid + 1;
                    else { hi = mid; ans = mid; if (c <= 48) break; }
                }
                // ballot-scan compaction of kept (<= ans) elements
                int base = 0;
#pragma unroll
                for (int s = 0; s < 2; ++s) {
                    bool p = __float_as_uint(dv[s]) <= ans;
                    unsigned long long bal = __ballot(p);
                    int pos = base + __popcll(bal & ((1ull << lane) - 1ull));
                    if (p && pos < CAP) { bd[rr][pos] = dv[s]; bj[rr][pos] = jv[s]; }
                    base += __popcll(bal);
                }
                if (lane == 0) {
                    bcnt[rr] = (base < CAP) ? base : CAP;
                    bthr[rr] = __uint_as_float(ans);
                }
            }
            __syncthreads();
        }
    }

    // Final exact top-32 per row: packed key (dist_bits<<32)|j, ties -> lower j
    for (int rr = wave; rr < 64; rr += 8) {
        int n = bcnt[rr]; if (n > CAP) n = CAP;
        unsigned long long k[2];
#pragma unroll
        for (int s = 0; s < 2; ++s) {
            int idxs = lane + s * 64;
            if (idxs < n)
                k[s] = ((unsigned long long)__float_as_uint(bd[rr][idxs]) << 32) |
                       (unsigned long long)bj[rr][idxs];
            else
                k[s] = ~0ull;
        }
        int* grow = graph + (size_t)(rbase + rr) * KSEL;
        for (int it = 0; it < KSEL; ++it) {
            unsigned long long m = k[0] < k[1] ? k[0] : k[1];
#pragma unroll
            for (int off = 32; off > 0; off >>= 1) {
                unsigned long long o = __shfl_xor(m, off);
                m = m < o ? m : o;
            }
            if (lane == 0) grow[it] = (int)(m & 0xffffffffull);
#pragma unroll
            for (int s = 0; s < 2; ++s) if (k[s] == m) k[s] = ~0ull;
        }
    }
}

// ---------------------------------------------------------------------------
// Kernel C: XWa[i][h]=x_i . w[h][0:64], XWb[i][h]=x_i . w[h][64:128],
//           OUTB[i][o]=x_i . w2[o][128:192]  (written directly to d_out).
// Block: 384 threads (one weight-slot each, weights in registers), 64 rows.
// ---------------------------------------------------------------------------
__global__ __launch_bounds__(384) void xw_kernel(const float* __restrict__ x,
                                                 const float* __restrict__ w,
                                                 const float* __restrict__ w2,
                                                 float* __restrict__ XWa,
                                                 float* __restrict__ XWb,
                                                 float* __restrict__ outb) {
    __shared__ float xs[64][64];
    const int t = threadIdx.x;
    const int rbase = blockIdx.x * 64;

    for (int idx = t; idx < 64 * 16; idx += 384) {
        int r = idx >> 4, q = idx & 15;
        ((float4*)xs[r])[q] = ((const float4*)(x + (size_t)(rbase + r) * IN_DIM))[q];
    }
    const int kind = t >> 7;       // 0:XWa 1:XWb 2:OUTB
    const int idx  = t & 127;
    const float* wp = (kind == 0) ? (w + (size_t)idx * 128)
                    : (kind == 1) ? (w + (size_t)idx * 128 + 64)
                                  : (w2 + (size_t)idx * 192 + 128);
    float4 wreg[16];
#pragma unroll
    for (int q = 0; q < 16; ++q) wreg[q] = ((const float4*)wp)[q];
    __syncthreads();

    for (int r = 0; r < 64; ++r) {
        float acc = 0.f;
#pragma unroll
        for (int q = 0; q < 16; ++q) {
            float4 xv = ((float4*)xs[r])[q];
            acc += xv.x * wreg[q].x + xv.y * wreg[q].y +
                   xv.z * wreg[q].z + xv.w * wreg[q].w;
        }
        size_t o = (size_t)(rbase + r) * 128 + idx;
        if (kind == 0)      XWa[o]  = acc;
        else if (kind == 1) XWb[o]  = acc;
        else                outb[o] = acc;
    }
}

// ---------------------------------------------------------------------------
// Kernel D: pooled[i][h] = mean_c clip(XWa[g[i][c]][h] + XWb[i][h], -1, 1)
// Block: 256 threads, 8 rows sequentially. Gathers are 512B coalesced rows.
// ---------------------------------------------------------------------------
__global__ __launch_bounds__(256) void pool_kernel(const int* __restrict__ graph,
                                                   const float* __restrict__ XWa,
                                                   const float* __restrict__ XWb,
                                                   float* __restrict__ pooled) {
    __shared__ float xwb[128];
    __shared__ int   gi[KSEL];
    __shared__ float part[256];
    const int t = threadIdx.x;
    const int rbase = blockIdx.x * 8;

    for (int rr = 0; rr < 8; ++rr) {
        int row = rbase + rr;
        if (t < KSEL) gi[t] = graph[(size_t)row * KSEL + t];
        if (t >= 64 && t < 192) xwb[t - 64] = XWb[(size_t)row * 128 + (t - 64)];
        __syncthreads();
        int h = t & 127, grp = t >> 7;
        float b = xwb[h];
        float acc = 0.f;
#pragma unroll
        for (int c = 0; c < 16; ++c) {
            int j = gi[grp * 16 + c];
            float v = XWa[(size_t)j * 128 + h] + b;
            acc += fminf(fmaxf(v, -1.f), 1.f);
        }
        part[t] = acc;
        __syncthreads();
        if (t < 128)
            pooled[(size_t)row * 128 + t] = (part[t] + part[t + 128]) * (1.f / 32.f);
        __syncthreads();
    }
}

// ---------------------------------------------------------------------------
// Kernel E: out[i][o] += pooled[i] . w2[o][0:128]   (out already holds OUTB)
// Block: 256 threads = 128 outs x 2 rows-in-flight; 64 rows per block.
// ---------------------------------------------------------------------------
__global__ __launch_bounds__(256) void out_kernel(const float* __restrict__ pooled,
                                                  const float* __restrict__ w2,
                                                  float* __restrict__ out) {
    __shared__ float ws2[128][132];   // pad 132 -> f4-aligned, banks spread
    __shared__ float pt[64][128];
    const int t = threadIdx.x;
    const int rbase = blockIdx.x * 64;

    for (int idx = t; idx < 128 * 32; idx += 256) {
        int o = idx >> 5, q = idx & 31;
        ((float4*)&ws2[o][0])[q] = ((const float4*)(w2 + (size_t)o * 192))[q];
    }
    for (int idx = t; idx < 64 * 32; idx += 256) {
        int r = idx >> 5, q = idx & 31;
        ((float4*)&pt[r][0])[q] = ((const float4*)(pooled + (size_t)(rbase + r) * 128))[q];
    }
    __syncthreads();

    const int o = t & 127, rsub = t >> 7;
    for (int rp = 0; rp < 32; ++rp) {
        int r = rp * 2 + rsub;
        float acc = 0.f;
#pragma unroll
        for (int q = 0; q < 32; ++q) {
            float4 pv = ((float4*)&pt[r][0])[q];
            float4 wv = ((float4*)&ws2[o][0])[q];
            acc += pv.x * wv.x + pv.y * wv.y + pv.z * wv.z + pv.w * wv.w;
        }
        size_t off = (size_t)(rbase + r) * 128 + o;
        out[off] += acc;
    }
}

// ---------------------------------------------------------------------------
extern "C" void kernel_launch(void* const* d_in, const int* in_sizes, int n_in,
                              void* d_out, int out_size, void* d_ws, size_t ws_size,
                              hipStream_t stream) {
    const float* x  = (const float*)d_in[0];   // (16384, 64)
    const float* w  = (const float*)d_in[1];   // (128, 128)
    const float* w2 = (const float*)d_in[2];   // (128, 192)
    float* out = (float*)d_out;                // (16384, 128)

    // workspace layout (all 16B-aligned)
    float* sq     = (float*)d_ws;                         // 16384 f
    int*   graph  = (int*)(sq + NPTS);                    // 16384*32 i
    float* XWa    = (float*)(graph + (size_t)NPTS * KSEL);// 16384*128 f
    float* XWb    = XWa + (size_t)NPTS * 128;             // 16384*128 f
    float* pooled = XWb + (size_t)NPTS * 128;             // 16384*128 f

    sqnorm_kernel<<<NPTS / 256, 256, 0, stream>>>(x, sq);
    knn_kernel<<<NPTS / 64, 512, 0, stream>>>(x, sq, graph);
    xw_kernel<<<NPTS / 64, 384, 0, stream>>>(x, w, w2, XWa, XWb, out);
    pool_kernel<<<NPTS / 8, 256, 0, stream>>>(graph, XWa, XWb, pooled);
    out_kernel<<<NPTS / 64, 256, 0, stream>>>(pooled, w2, out);
}

// Round 4
// 1186.452 us; speedup vs baseline: 11.6766x; 1.4934x over previous
//
#include <hip/hip_runtime.h>

// Problem constants
#define NPTS    16384
#define IN_DIM  64
#define HID     128
#define KSEL    32

#define CAP     192              // per-row candidate slots (64 kept + 128/tile burst)
#define EPS_SLACK 2e-3f          // >= 2x worst-case bf16-split distance error
#define POSINF  __int_as_float(0x7f800000)

typedef __attribute__((ext_vector_type(8))) short bf16x8;   // 8 bf16 = 4 VGPR
typedef __attribute__((ext_vector_type(4))) float f32x4;    // MFMA accumulator

__device__ inline unsigned short f2bf(float f) {            // RN-even f32->bf16
    unsigned u = __float_as_uint(f);
    u += 0x7fffu + ((u >> 16) & 1u);
    return (unsigned short)(u >> 16);
}
__device__ inline float bf2f(unsigned short h) {
    return __uint_as_float(((unsigned)h) << 16);
}

// ---------------------------------------------------------------------------
// Kernel A: prep — row sqnorm (fp32) + bf16 hi/lo split of x.
// ---------------------------------------------------------------------------
__global__ __launch_bounds__(256) void prep_kernel(const float* __restrict__ x,
                                                   float* __restrict__ sq,
                                                   unsigned short* __restrict__ xhi,
                                                   unsigned short* __restrict__ xlo) {
    int i = blockIdx.x * 256 + threadIdx.x;
    const float4* xr = (const float4*)(x + (size_t)i * IN_DIM);
    uint4* hd = (uint4*)(xhi + (size_t)i * IN_DIM);
    uint4* ld = (uint4*)(xlo + (size_t)i * IN_DIM);
    float s = 0.f;
#pragma unroll
    for (int q = 0; q < 8; ++q) {
        float4 a = xr[2 * q], b = xr[2 * q + 1];
        float e[8] = {a.x, a.y, a.z, a.w, b.x, b.y, b.z, b.w};
        unsigned hw[8], lw[8];
#pragma unroll
        for (int j = 0; j < 8; ++j) {
            s += e[j] * e[j];
            unsigned short h = f2bf(e[j]);
            unsigned short l = f2bf(e[j] - bf2f(h));
            hw[j] = h; lw[j] = l;
        }
        hd[q] = make_uint4(hw[0] | (hw[1] << 16), hw[2] | (hw[3] << 16),
                           hw[4] | (hw[5] << 16), hw[6] | (hw[7] << 16));
        ld[q] = make_uint4(lw[0] | (lw[1] << 16), lw[2] | (lw[3] << 16),
                           lw[4] | (lw[5] << 16), lw[6] | (lw[7] << 16));
    }
    sq[i] = s;
}

// ---------------------------------------------------------------------------
// Kernel B: MFMA distance GEMM (bf16 3-term split) + streaming top-32.
// Block: 256 thr (4 waves), 64 rows (16/wave, wave-private selection).
// Tile: 128 cols; 8 col-tiles of 16x16x32 MFMA, K=64 (2 k-halves), 3 terms.
// LDS B-tiles swizzled (16B slot ^= row&7) -> conflict-free ds_read_b128.
// Approx filter with EPS_SLACK guarantees true top-32 survives; final exact
// fp32 re-verification of <=CAP candidates per row before extraction.
// ---------------------------------------------------------------------------
__global__ __launch_bounds__(256) void knn_kernel(const float* __restrict__ x,
                                                  const unsigned short* __restrict__ xhi,
                                                  const unsigned short* __restrict__ xlo,
                                                  const float* __restrict__ sq,
                                                  int* __restrict__ graph) {
    __shared__ unsigned short Bh[128 * 64];   // 16 KB, swizzled slots
    __shared__ unsigned short Bl[128 * 64];   // 16 KB
    __shared__ float sBs[128];
    __shared__ float bd[64][CAP];             // 48 KB
    __shared__ unsigned short bj[64][CAP];    // 24 KB
    __shared__ int   bcnt[64];
    __shared__ float bthr[64];

    const int t    = threadIdx.x;
    const int lane = t & 63;
    const int wave = t >> 6;        // 0..3
    const int g    = lane >> 4;     // 0..3
    const int li   = lane & 15;     // 0..15
    const int rbase = blockIdx.x * 64;
    const int wrow  = wave * 16;    // wave's first block-local row

    if (t < 64) { bcnt[t] = 0; bthr[t] = POSINF; }

    // A fragments (tile-invariant) from global: lane holds row wrow+li,
    // k = kh*32 + g*8 + j.
    bf16x8 ah[2], al[2];
    {
        const size_t ro = (size_t)(rbase + wrow + li) * IN_DIM;
#pragma unroll
        for (int kh = 0; kh < 2; ++kh) {
            ah[kh] = *(const bf16x8*)(xhi + ro + kh * 32 + g * 8);
            al[kh] = *(const bf16x8*)(xlo + ro + kh * 32 + g * 8);
        }
    }
    // sqA for this lane's 4 C-rows (row = wrow + g*4 + r)
    float sar[4];
#pragma unroll
    for (int r = 0; r < 4; ++r) sar[r] = sq[rbase + wrow + g * 4 + r];
    __syncthreads();

    for (int tile = 0; tile < NPTS / 128; ++tile) {
        const int cb = tile * 128;
        // ---- stage B hi/lo with slot swizzle + sBs
        for (int s = t; s < 1024; s += 256) {
            int row = s >> 3, sl = s & 7;
            int dsl = sl ^ (row & 7);
            *(uint4*)&Bh[row * 64 + dsl * 8] =
                *(const uint4*)(xhi + (size_t)(cb + row) * IN_DIM + sl * 8);
            *(uint4*)&Bl[row * 64 + dsl * 8] =
                *(const uint4*)(xlo + (size_t)(cb + row) * IN_DIM + sl * 8);
        }
        if (t < 128) sBs[t] = sq[cb + t];
        __syncthreads();

        // ---- MFMA: 8 col-tiles, acc = 3-term split dot
        f32x4 acc[8];
#pragma unroll
        for (int ct = 0; ct < 8; ++ct) {
            const int p  = ct * 16 + li;          // B point within tile
            const int pb = p * 64;
            const int s0 = (g)     ^ (p & 7);     // k-half 0 slot
            const int s1 = (4 + g) ^ (p & 7);     // k-half 1 slot
            bf16x8 bh0 = *(const bf16x8*)&Bh[pb + s0 * 8];
            bf16x8 bh1 = *(const bf16x8*)&Bh[pb + s1 * 8];
            bf16x8 bl0 = *(const bf16x8*)&Bl[pb + s0 * 8];
            bf16x8 bl1 = *(const bf16x8*)&Bl[pb + s1 * 8];
            f32x4 a = {0.f, 0.f, 0.f, 0.f};
            a = __builtin_amdgcn_mfma_f32_16x16x32_bf16(ah[0], bh0, a, 0, 0, 0);
            a = __builtin_amdgcn_mfma_f32_16x16x32_bf16(ah[1], bh1, a, 0, 0, 0);
            a = __builtin_amdgcn_mfma_f32_16x16x32_bf16(ah[0], bl0, a, 0, 0, 0);
            a = __builtin_amdgcn_mfma_f32_16x16x32_bf16(ah[1], bl1, a, 0, 0, 0);
            a = __builtin_amdgcn_mfma_f32_16x16x32_bf16(al[0], bh0, a, 0, 0, 0);
            a = __builtin_amdgcn_mfma_f32_16x16x32_bf16(al[1], bh1, a, 0, 0, 0);
            acc[ct] = a;
        }

        // ---- epilogue: d = sqA + sqB - 2*dot ; filter -> wave-private buffer
        float thr[4];
#pragma unroll
        for (int r = 0; r < 4; ++r) thr[r] = bthr[wrow + g * 4 + r];
#pragma unroll
        for (int ct = 0; ct < 8; ++ct) {
            float sbv = sBs[ct * 16 + li];
#pragma unroll
            for (int r = 0; r < 4; ++r) {
                float d = fmaf(-2.f, acc[ct][r], sar[r] + sbv);
                if (d <= thr[r]) {
                    int row = wrow + g * 4 + r;
                    int pos = atomicAdd(&bcnt[row], 1);
                    if (pos < CAP) {
                        bd[row][pos] = fmaxf(d, 0.f);
                        bj[row][pos] = (unsigned short)(cb + ct * 16 + li);
                    }
                }
            }
        }
        __threadfence_block();   // wave's inserts visible to its own reads

        // ---- wave-local compaction (no barrier): trigger n > 64
        unsigned long long need =
            __ballot((lane < 16) && (bcnt[wrow + lane] > 64));
        while (need) {
            int rr = wrow + (__ffsll((long long)need) - 1);
            need &= need - 1;
            int n = bcnt[rr]; n = n < CAP ? n : CAP;
            unsigned ud[3]; unsigned short jv[3]; float dv[3];
#pragma unroll
            for (int s = 0; s < 3; ++s) {
                int idx = lane + s * 64;
                bool v = idx < n;
                dv[s] = v ? bd[rr][idx] : POSINF;
                jv[s] = v ? bj[rr][idx] : 0;
                ud[s] = __float_as_uint(dv[s]);
            }
            // bisect smallest ans with count>=32 (early exit count<=64)
            unsigned lo = 0u, hi = 0x7f800000u, ans = hi;
            for (int it = 0; it < 31 && lo < hi; ++it) {
                unsigned mid = lo + ((hi - lo) >> 1);
                int c = 0;
#pragma unroll
                for (int s = 0; s < 3; ++s)
                    c += __popcll(__ballot(ud[s] <= mid));
                if (c < 32) lo = mid + 1;
                else { hi = mid; ans = mid; if (c <= 64) break; }
            }
            float ansf = __uint_as_float(ans) + EPS_SLACK;  // slack: keep band
            int base = 0;
#pragma unroll
            for (int s = 0; s < 3; ++s) {
                bool p = dv[s] <= ansf;
                unsigned long long bal = __ballot(p);
                int pos = base + __popcll(bal & ((1ull << lane) - 1ull));
                if (p && pos < CAP) { bd[rr][pos] = dv[s]; bj[rr][pos] = jv[s]; }
                base += __popcll(bal);
            }
            if (lane == 0) {
                bcnt[rr] = base < CAP ? base : CAP;
                bthr[rr] = ansf;
            }
        }
        __syncthreads();   // before next tile overwrites Bh/Bl/sBs
    }

    // ---- final: exact fp32 re-verification of survivors, then top-32
    for (int i = 0; i < 16; ++i) {
        int rr = wrow + i;
        int n = bcnt[rr]; n = n < CAP ? n : CAP;
        float sqa = sq[rbase + rr];
        const float4* xa = (const float4*)(x + (size_t)(rbase + rr) * IN_DIM);
        unsigned long long key[3];
#pragma unroll
        for (int s = 0; s < 3; ++s) {
            int idx = lane + s * 64;
            if (idx < n) {
                int j = bj[rr][idx];
                const float4* xb = (const float4*)(x + (size_t)j * IN_DIM);
                float dot = 0.f;
#pragma unroll
                for (int q = 0; q < 16; ++q) {
                    float4 a = xa[q], b = xb[q];
                    dot += a.x * b.x + a.y * b.y + a.z * b.z + a.w * b.w;
                }
                float d = fmaxf(fmaf(-2.f, dot, sqa + sq[j]), 0.f);
                key[s] = ((unsigned long long)__float_as_uint(d) << 32) |
                         (unsigned long long)(unsigned)j;
            } else key[s] = ~0ull;
        }
        int* grow = graph + (size_t)(rbase + rr) * KSEL;
        for (int it = 0; it < KSEL; ++it) {
            unsigned long long m01 = key[0] < key[1] ? key[0] : key[1];
            unsigned long long m = m01 < key[2] ? m01 : key[2];
#pragma unroll
            for (int off = 32; off > 0; off >>= 1) {
                unsigned long long o = __shfl_xor(m, off);
                m = m < o ? m : o;
            }
            if (lane == 0) grow[it] = (int)(m & 0xffffffffull);
#pragma unroll
            for (int s = 0; s < 3; ++s) if (key[s] == m) key[s] = ~0ull;
        }
    }
}

// ---------------------------------------------------------------------------
// Kernel C: XWa[i][h]=x_i.w[h][0:64], XWb[i][h]=x_i.w[h][64:128],
//           OUTB[i][o]=x_i.w2[o][128:192] (direct to d_out).
// ---------------------------------------------------------------------------
__global__ __launch_bounds__(384) void xw_kernel(const float* __restrict__ x,
                                                 const float* __restrict__ w,
                                                 const float* __restrict__ w2,
                                                 float* __restrict__ XWa,
                                                 float* __restrict__ XWb,
                                                 float* __restrict__ outb) {
    __shared__ float xs[64][64];
    const int t = threadIdx.x;
    const int rbase = blockIdx.x * 64;

    for (int idx = t; idx < 64 * 16; idx += 384) {
        int r = idx >> 4, q = idx & 15;
        ((float4*)xs[r])[q] = ((const float4*)(x + (size_t)(rbase + r) * IN_DIM))[q];
    }
    const int kind = t >> 7;
    const int idx  = t & 127;
    const float* wp = (kind == 0) ? (w + (size_t)idx * 128)
                    : (kind == 1) ? (w + (size_t)idx * 128 + 64)
                                  : (w2 + (size_t)idx * 192 + 128);
    float4 wreg[16];
#pragma unroll
    for (int q = 0; q < 16; ++q) wreg[q] = ((const float4*)wp)[q];
    __syncthreads();

    for (int r = 0; r < 64; ++r) {
        float acc = 0.f;
#pragma unroll
        for (int q = 0; q < 16; ++q) {
            float4 xv = ((float4*)xs[r])[q];
            acc += xv.x * wreg[q].x + xv.y * wreg[q].y +
                   xv.z * wreg[q].z + xv.w * wreg[q].w;
        }
        size_t o = (size_t)(rbase + r) * 128 + idx;
        if (kind == 0)      XWa[o]  = acc;
        else if (kind == 1) XWb[o]  = acc;
        else                outb[o] = acc;
    }
}

// ---------------------------------------------------------------------------
// Kernel D: pooled[i][h] = mean_c clip(XWa[g[i][c]][h] + XWb[i][h], -1, 1)
// ---------------------------------------------------------------------------
__global__ __launch_bounds__(256) void pool_kernel(const int* __restrict__ graph,
                                                   const float* __restrict__ XWa,
                                                   const float* __restrict__ XWb,
                                                   float* __restrict__ pooled) {
    __shared__ float xwb[128];
    __shared__ int   gi[KSEL];
    __shared__ float part[256];
    const int t = threadIdx.x;
    const int rbase = blockIdx.x * 8;

    for (int rr = 0; rr < 8; ++rr) {
        int row = rbase + rr;
        if (t < KSEL) gi[t] = graph[(size_t)row * KSEL + t];
        if (t >= 64 && t < 192) xwb[t - 64] = XWb[(size_t)row * 128 + (t - 64)];
        __syncthreads();
        int h = t & 127, grp = t >> 7;
        float b = xwb[h];
        float acc = 0.f;
#pragma unroll
        for (int c = 0; c < 16; ++c) {
            int j = gi[grp * 16 + c];
            float v = XWa[(size_t)j * 128 + h] + b;
            acc += fminf(fmaxf(v, -1.f), 1.f);
        }
        part[t] = acc;
        __syncthreads();
        if (t < 128)
            pooled[(size_t)row * 128 + t] = (part[t] + part[t + 128]) * (1.f / 32.f);
        __syncthreads();
    }
}

// ---------------------------------------------------------------------------
// Kernel E: out[i][o] += pooled[i] . w2[o][0:128]  (out holds OUTB)
// ---------------------------------------------------------------------------
__global__ __launch_bounds__(256) void out_kernel(const float* __restrict__ pooled,
                                                  const float* __restrict__ w2,
                                                  float* __restrict__ out) {
    __shared__ float ws2[128][132];
    __shared__ float pt[64][128];
    const int t = threadIdx.x;
    const int rbase = blockIdx.x * 64;

    for (int idx = t; idx < 128 * 32; idx += 256) {
        int o = idx >> 5, q = idx & 31;
        ((float4*)&ws2[o][0])[q] = ((const float4*)(w2 + (size_t)o * 192))[q];
    }
    for (int idx = t; idx < 64 * 32; idx += 256) {
        int r = idx >> 5, q = idx & 31;
        ((float4*)&pt[r][0])[q] = ((const float4*)(pooled + (size_t)(rbase + r) * 128))[q];
    }
    __syncthreads();

    const int o = t & 127, rsub = t >> 7;
    for (int rp = 0; rp < 32; ++rp) {
        int r = rp * 2 + rsub;
        float acc = 0.f;
#pragma unroll
        for (int q = 0; q < 32; ++q) {
            float4 pv = ((float4*)&pt[r][0])[q];
            float4 wv = ((float4*)&ws2[o][0])[q];
            acc += pv.x * wv.x + pv.y * wv.y + pv.z * wv.z + pv.w * wv.w;
        }
        size_t off = (size_t)(rbase + r) * 128 + o;
        out[off] += acc;
    }
}

// ---------------------------------------------------------------------------
extern "C" void kernel_launch(void* const* d_in, const int* in_sizes, int n_in,
                              void* d_out, int out_size, void* d_ws, size_t ws_size,
                              hipStream_t stream) {
    const float* x  = (const float*)d_in[0];   // (16384, 64)
    const float* w  = (const float*)d_in[1];   // (128, 128)
    const float* w2 = (const float*)d_in[2];   // (128, 192)
    float* out = (float*)d_out;                // (16384, 128)

    // workspace (26.07 MB): pooled aliases xhi/xlo (pool runs after knn)
    float* sq     = (float*)d_ws;                           // 64 KB
    int*   graph  = (int*)(sq + NPTS);                      // 2 MB
    float* XWa    = (float*)(graph + (size_t)NPTS * KSEL);  // 8 MB
    float* XWb    = XWa + (size_t)NPTS * HID;               // 8 MB
    float* region = XWb + (size_t)NPTS * HID;               // 8 MB
    unsigned short* xhi = (unsigned short*)region;          // 2 MB
    unsigned short* xlo = xhi + (size_t)NPTS * IN_DIM;      // 2 MB
    float* pooled = region;                                 // aliases xhi/xlo

    prep_kernel<<<NPTS / 256, 256, 0, stream>>>(x, sq, xhi, xlo);
    knn_kernel<<<NPTS / 64, 256, 0, stream>>>(x, xhi, xlo, sq, graph);
    xw_kernel<<<NPTS / 64, 384, 0, stream>>>(x, w, w2, XWa, XWb, out);
    pool_kernel<<<NPTS / 8, 256, 0, stream>>>(graph, XWa, XWb, pooled);
    out_kernel<<<NPTS / 64, 256, 0, stream>>>(pooled, w2, out);
}

// Round 6
// 785.310 us; speedup vs baseline: 17.6411x; 1.5108x over previous
//
#include <hip/hip_runtime.h>

// Problem constants
#define NPTS    16384
#define IN_DIM  64
#define HID     128
#define KSEL    32

#define CAP     192              // per-row candidate slots
#define EPS_SLACK 0.03f          // >= 2x worst-case bf16-split distance error
#define COMPACT_TRIG 60          // compact when n > this
#define WIN_HI  48               // bisect early-exit when count <= this
#define POSINF  __int_as_float(0x7f800000)

typedef __attribute__((ext_vector_type(8))) short bf16x8;   // 8 bf16 = 4 VGPR
typedef __attribute__((ext_vector_type(4))) float f32x4;    // MFMA accumulator

__device__ inline unsigned short f2bf(float f) {            // RN-even f32->bf16
    unsigned u = __float_as_uint(f);
    u += 0x7fffu + ((u >> 16) & 1u);
    return (unsigned short)(u >> 16);
}
__device__ inline float bf2f(unsigned short h) {
    return __uint_as_float(((unsigned)h) << 16);
}

// ---------------------------------------------------------------------------
// Kernel A: prep — row sqnorm (fp32) + bf16 hi/lo split of x.
// ---------------------------------------------------------------------------
__global__ __launch_bounds__(256) void prep_kernel(const float* __restrict__ x,
                                                   float* __restrict__ sq,
                                                   unsigned short* __restrict__ xhi,
                                                   unsigned short* __restrict__ xlo) {
    int i = blockIdx.x * 256 + threadIdx.x;
    const float4* xr = (const float4*)(x + (size_t)i * IN_DIM);
    uint4* hd = (uint4*)(xhi + (size_t)i * IN_DIM);
    uint4* ld = (uint4*)(xlo + (size_t)i * IN_DIM);
    float s = 0.f;
#pragma unroll
    for (int q = 0; q < 8; ++q) {
        float4 a = xr[2 * q], b = xr[2 * q + 1];
        float e[8] = {a.x, a.y, a.z, a.w, b.x, b.y, b.z, b.w};
        unsigned hw[8], lw[8];
#pragma unroll
        for (int j = 0; j < 8; ++j) {
            s += e[j] * e[j];
            unsigned short h = f2bf(e[j]);
            unsigned short l = f2bf(e[j] - bf2f(h));
            hw[j] = h; lw[j] = l;
        }
        hd[q] = make_uint4(hw[0] | (hw[1] << 16), hw[2] | (hw[3] << 16),
                           hw[4] | (hw[5] << 16), hw[6] | (hw[7] << 16));
        ld[q] = make_uint4(lw[0] | (lw[1] << 16), lw[2] | (lw[3] << 16),
                           lw[4] | (lw[5] << 16), lw[6] | (lw[7] << 16));
    }
    sq[i] = s;
}

// ---------------------------------------------------------------------------
// Kernel B: MFMA distance GEMM (bf16 3-term split) + streaming top-32.
// Block: 1024 thr (16 waves = 4 waves/SIMD), 64 queries. Grid: 256 (=CUs).
// Wave w: coltile ct=w&7 (16 cols), rowtile pair rp=w>>3 (rows rp*32..+31).
//   -> B fragments read ONCE per wave (4 ds_read_b128), reused for 2 rowtiles.
// Tile: 128 cols; K=64 (2 k-halves), 3-term split -> 6 MFMA per 16x16 C-tile.
// LDS B-tiles swizzled (16B slot ^= row&7) -> conflict-free ds_read_b128.
// Selection: EPS-slack filter -> per-row LDS buffer (CAP 192, worst-case
// burst 60+128 <= 192 provable) -> wave-local bisect-compact (each wave owns
// rows w*4..w*4+3) -> exact fp32 re-verification -> top-32 extract.
// ---------------------------------------------------------------------------
__global__ __launch_bounds__(1024, 4) void knn_kernel(const float* __restrict__ x,
                                                      const unsigned short* __restrict__ xhi,
                                                      const unsigned short* __restrict__ xlo,
                                                      const float* __restrict__ sq,
                                                      int* __restrict__ graph) {
    __shared__ unsigned short Bh[128 * 64];   // 16 KB, swizzled slots
    __shared__ unsigned short Bl[128 * 64];   // 16 KB
    __shared__ float sBs[128];
    __shared__ float bd[64][CAP];             // 48 KB
    __shared__ unsigned short bj[64][CAP];    // 24 KB
    __shared__ int   bcnt[64];
    __shared__ float bthr[64];

    const int t    = threadIdx.x;
    const int lane = t & 63;
    const int wave = t >> 6;        // 0..15
    const int g    = lane >> 4;     // 0..3
    const int li   = lane & 15;     // 0..15
    const int ct   = wave & 7;      // coltile (16 cols)
    const int rp   = wave >> 3;     // rowtile pair: rows rp*32 .. rp*32+31
    const int rbase = blockIdx.x * 64;
    const int orow  = wave * 4;     // owned rows for compact/final (block-local)

    if (t < 64) { bcnt[t] = 0; bthr[t] = POSINF; }

    // A fragments (tile-invariant): rowtile rt' in {0,1} -> row rp*32+rt'*16+li,
    // k = kh*32 + g*8 + j.
    bf16x8 ah[2][2], al[2][2];
#pragma unroll
    for (int rt = 0; rt < 2; ++rt) {
        const size_t ro = (size_t)(rbase + rp * 32 + rt * 16 + li) * IN_DIM;
#pragma unroll
        for (int kh = 0; kh < 2; ++kh) {
            ah[rt][kh] = *(const bf16x8*)(xhi + ro + kh * 32 + g * 8);
            al[rt][kh] = *(const bf16x8*)(xlo + ro + kh * 32 + g * 8);
        }
    }
    // sqA for this lane's C rows: row = rp*32 + rt*16 + g*4 + r
    float sar[2][4];
#pragma unroll
    for (int rt = 0; rt < 2; ++rt)
#pragma unroll
        for (int r = 0; r < 4; ++r)
            sar[rt][r] = sq[rbase + rp * 32 + rt * 16 + g * 4 + r];

    for (int tile = 0; tile < NPTS / 128; ++tile) {
        const int cb = tile * 128;
        // ---- stage B hi/lo with slot swizzle + sBs (1 entry per thread)
        {
            int row = t >> 3, sl = t & 7;
            int dsl = sl ^ (row & 7);
            *(uint4*)&Bh[row * 64 + dsl * 8] =
                *(const uint4*)(xhi + (size_t)(cb + row) * IN_DIM + sl * 8);
            *(uint4*)&Bl[row * 64 + dsl * 8] =
                *(const uint4*)(xlo + (size_t)(cb + row) * IN_DIM + sl * 8);
            if (t < 128) sBs[t] = sq[cb + t];
        }
        __syncthreads();

        // ---- B fragments for this wave's coltile (read once, reuse 2x)
        const int p  = ct * 16 + li;
        const int pb = p * 64;
        const int s0 = (g)     ^ (p & 7);
        const int s1 = (4 + g) ^ (p & 7);
        bf16x8 bh0 = *(const bf16x8*)&Bh[pb + s0 * 8];
        bf16x8 bh1 = *(const bf16x8*)&Bh[pb + s1 * 8];
        bf16x8 bl0 = *(const bf16x8*)&Bl[pb + s0 * 8];
        bf16x8 bl1 = *(const bf16x8*)&Bl[pb + s1 * 8];
        float sbv = sBs[p];

        // ---- MFMA + epilogue per rowtile
#pragma unroll
        for (int rt = 0; rt < 2; ++rt) {
            f32x4 a = {0.f, 0.f, 0.f, 0.f};
            a = __builtin_amdgcn_mfma_f32_16x16x32_bf16(ah[rt][0], bh0, a, 0, 0, 0);
            a = __builtin_amdgcn_mfma_f32_16x16x32_bf16(ah[rt][1], bh1, a, 0, 0, 0);
            a = __builtin_amdgcn_mfma_f32_16x16x32_bf16(ah[rt][0], bl0, a, 0, 0, 0);
            a = __builtin_amdgcn_mfma_f32_16x16x32_bf16(ah[rt][1], bl1, a, 0, 0, 0);
            a = __builtin_amdgcn_mfma_f32_16x16x32_bf16(al[rt][0], bh0, a, 0, 0, 0);
            a = __builtin_amdgcn_mfma_f32_16x16x32_bf16(al[rt][1], bh1, a, 0, 0, 0);
#pragma unroll
            for (int r = 0; r < 4; ++r) {
                int row = rp * 32 + rt * 16 + g * 4 + r;
                float d = fmaf(-2.f, a[r], sar[rt][r] + sbv);
                if (d <= bthr[row]) {
                    int pos = atomicAdd(&bcnt[row], 1);
                    if (pos < CAP) {
                        bd[row][pos] = fmaxf(d, 0.f);
                        bj[row][pos] = (unsigned short)(cb + p);
                    }
                }
            }
        }
        __syncthreads();

        // ---- wave-local compaction of owned rows: trigger n > COMPACT_TRIG
        unsigned long long need =
            __ballot((lane < 4) && (bcnt[orow + lane] > COMPACT_TRIG));
        while (need) {
            int rr = orow + (__ffsll((long long)need) - 1);
            need &= need - 1;
            int n = bcnt[rr]; n = n < CAP ? n : CAP;
            unsigned ud[3]; unsigned short jv[3]; float dv[3];
#pragma unroll
            for (int s = 0; s < 3; ++s) {
                int idx = lane + s * 64;
                bool v = idx < n;
                dv[s] = v ? bd[rr][idx] : POSINF;
                jv[s] = v ? bj[rr][idx] : 0;
                ud[s] = __float_as_uint(dv[s]);
            }
            // bisect smallest ans with count>=32 (early exit count<=WIN_HI)
            unsigned lo = 0u, hi = __float_as_uint(bthr[rr]), ans = hi;
            for (int it = 0; it < 24 && lo < hi; ++it) {
                unsigned mid = lo + ((hi - lo) >> 1);
                int c = 0;
#pragma unroll
                for (int s = 0; s < 3; ++s)
                    c += __popcll(__ballot(ud[s] <= mid));
                if (c < 32) lo = mid + 1;
                else { hi = mid; ans = mid; if (c <= WIN_HI) break; }
            }
            float ansf = __uint_as_float(ans) + EPS_SLACK;  // slack keeps band
            int base = 0;
#pragma unroll
            for (int s = 0; s < 3; ++s) {
                bool pk = dv[s] <= ansf;
                unsigned long long bal = __ballot(pk);
                int pos = base + __popcll(bal & ((1ull << lane) - 1ull));
                if (pk && pos < CAP) { bd[rr][pos] = dv[s]; bj[rr][pos] = jv[s]; }
                base += __popcll(bal);
            }
            if (lane == 0) {
                bcnt[rr] = base < CAP ? base : CAP;
                bthr[rr] = ansf;
            }
        }
        __syncthreads();   // before next tile overwrites Bh/Bl/sBs
    }

    // ---- final: exact fp32 re-verification of survivors, then top-32
    for (int i = 0; i < 4; ++i) {
        int rr = orow + i;
        int n = bcnt[rr]; n = n < CAP ? n : CAP;
        float sqa = sq[rbase + rr];
        const float4* xa = (const float4*)(x + (size_t)(rbase + rr) * IN_DIM);
        unsigned long long key[3];
#pragma unroll
        for (int s = 0; s < 3; ++s) {
            int idx = lane + s * 64;
            if (idx < n) {
                int j = bj[rr][idx];
                const float4* xb = (const float4*)(x + (size_t)j * IN_DIM);
                float dot = 0.f;
#pragma unroll
                for (int q = 0; q < 16; ++q) {
                    float4 a = xa[q], b = xb[q];
                    dot += a.x * b.x + a.y * b.y + a.z * b.z + a.w * b.w;
                }
                float d = fmaxf(fmaf(-2.f, dot, sqa + sq[j]), 0.f);
                key[s] = ((unsigned long long)__float_as_uint(d) << 32) |
                         (unsigned long long)(unsigned)j;
            } else key[s] = ~0ull;
        }
        int* grow = graph + (size_t)(rbase + rr) * KSEL;
        for (int it = 0; it < KSEL; ++it) {
            unsigned long long m01 = key[0] < key[1] ? key[0] : key[1];
            unsigned long long m = m01 < key[2] ? m01 : key[2];
#pragma unroll
            for (int off = 32; off > 0; off >>= 1) {
                unsigned long long o = __shfl_xor(m, off);
                m = m < o ? m : o;
            }
            if (lane == 0) grow[it] = (int)(m & 0xffffffffull);
#pragma unroll
            for (int s = 0; s < 3; ++s) if (key[s] == m) key[s] = ~0ull;
        }
    }
}

// ---------------------------------------------------------------------------
// Kernel C: XWa[i][h]=x_i.w[h][0:64], XWb[i][h]=x_i.w[h][64:128],
//           OUTB[i][o]=x_i.w2[o][128:192] (direct to d_out).
// ---------------------------------------------------------------------------
__global__ __launch_bounds__(384) void xw_kernel(const float* __restrict__ x,
                                                 const float* __restrict__ w,
                                                 const float* __restrict__ w2,
                                                 float* __restrict__ XWa,
                                                 float* __restrict__ XWb,
                                                 float* __restrict__ outb) {
    __shared__ float xs[64][64];
    const int t = threadIdx.x;
    const int rbase = blockIdx.x * 64;

    for (int idx = t; idx < 64 * 16; idx += 384) {
        int r = idx >> 4, q = idx & 15;
        ((float4*)xs[r])[q] = ((const float4*)(x + (size_t)(rbase + r) * IN_DIM))[q];
    }
    const int kind = t >> 7;
    const int idx  = t & 127;
    const float* wp = (kind == 0) ? (w + (size_t)idx * 128)
                    : (kind == 1) ? (w + (size_t)idx * 128 + 64)
                                  : (w2 + (size_t)idx * 192 + 128);
    float4 wreg[16];
#pragma unroll
    for (int q = 0; q < 16; ++q) wreg[q] = ((const float4*)wp)[q];
    __syncthreads();

    for (int r = 0; r < 64; ++r) {
        float acc = 0.f;
#pragma unroll
        for (int q = 0; q < 16; ++q) {
            float4 xv = ((float4*)xs[r])[q];
            acc += xv.x * wreg[q].x + xv.y * wreg[q].y +
                   xv.z * wreg[q].z + xv.w * wreg[q].w;
        }
        size_t o = (size_t)(rbase + r) * 128 + idx;
        if (kind == 0)      XWa[o]  = acc;
        else if (kind == 1) XWb[o]  = acc;
        else                outb[o] = acc;
    }
}

// ---------------------------------------------------------------------------
// Kernel D: pooled[i][h] = mean_c clip(XWa[g[i][c]][h] + XWb[i][h], -1, 1)
// ---------------------------------------------------------------------------
__global__ __launch_bounds__(256) void pool_kernel(const int* __restrict__ graph,
                                                   const float* __restrict__ XWa,
                                                   const float* __restrict__ XWb,
                                                   float* __restrict__ pooled) {
    __shared__ float xwb[128];
    __shared__ int   gi[KSEL];
    __shared__ float part[256];
    const int t = threadIdx.x;
    const int rbase = blockIdx.x * 8;

    for (int rr = 0; rr < 8; ++rr) {
        int row = rbase + rr;
        if (t < KSEL) gi[t] = graph[(size_t)row * KSEL + t];
        if (t >= 64 && t < 192) xwb[t - 64] = XWb[(size_t)row * 128 + (t - 64)];
        __syncthreads();
        int h = t & 127, grp = t >> 7;
        float b = xwb[h];
        float acc = 0.f;
#pragma unroll
        for (int c = 0; c < 16; ++c) {
            int j = gi[grp * 16 + c];
            float v = XWa[(size_t)j * 128 + h] + b;
            acc += fminf(fmaxf(v, -1.f), 1.f);
        }
        part[t] = acc;
        __syncthreads();
        if (t < 128)
            pooled[(size_t)row * 128 + t] = (part[t] + part[t + 128]) * (1.f / 32.f);
        __syncthreads();
    }
}

// ---------------------------------------------------------------------------
// Kernel E: out[i][o] += pooled[i] . w2[o][0:128]  (out holds OUTB)
// ---------------------------------------------------------------------------
__global__ __launch_bounds__(256) void out_kernel(const float* __restrict__ pooled,
                                                  const float* __restrict__ w2,
                                                  float* __restrict__ out) {
    __shared__ float ws2[128][132];
    __shared__ float pt[64][128];
    const int t = threadIdx.x;
    const int rbase = blockIdx.x * 64;

    for (int idx = t; idx < 128 * 32; idx += 256) {
        int o = idx >> 5, q = idx & 31;
        ((float4*)&ws2[o][0])[q] = ((const float4*)(w2 + (size_t)o * 192))[q];
    }
    for (int idx = t; idx < 64 * 32; idx += 256) {
        int r = idx >> 5, q = idx & 31;
        ((float4*)&pt[r][0])[q] = ((const float4*)(pooled + (size_t)(rbase + r) * 128))[q];
    }
    __syncthreads();

    const int o = t & 127, rsub = t >> 7;
    for (int rp = 0; rp < 32; ++rp) {
        int r = rp * 2 + rsub;
        float acc = 0.f;
#pragma unroll
        for (int q = 0; q < 32; ++q) {
            float4 pv = ((float4*)&pt[r][0])[q];
            float4 wv = ((float4*)&ws2[o][0])[q];
            acc += pv.x * wv.x + pv.y * wv.y + pv.z * wv.z + pv.w * wv.w;
        }
        size_t off = (size_t)(rbase + r) * 128 + o;
        out[off] += acc;
    }
}

// ---------------------------------------------------------------------------
extern "C" void kernel_launch(void* const* d_in, const int* in_sizes, int n_in,
                              void* d_out, int out_size, void* d_ws, size_t ws_size,
                              hipStream_t stream) {
    const float* x  = (const float*)d_in[0];   // (16384, 64)
    const float* w  = (const float*)d_in[1];   // (128, 128)
    const float* w2 = (const float*)d_in[2];   // (128, 192)
    float* out = (float*)d_out;                // (16384, 128)

    // workspace (26.07 MB): pooled aliases xhi/xlo (pool runs after knn)
    float* sq     = (float*)d_ws;                           // 64 KB
    int*   graph  = (int*)(sq + NPTS);                      // 2 MB
    float* XWa    = (float*)(graph + (size_t)NPTS * KSEL);  // 8 MB
    float* XWb    = XWa + (size_t)NPTS * HID;               // 8 MB
    float* region = XWb + (size_t)NPTS * HID;               // 8 MB
    unsigned short* xhi = (unsigned short*)region;          // 2 MB
    unsigned short* xlo = xhi + (size_t)NPTS * IN_DIM;      // 2 MB
    float* pooled = region;                                 // aliases xhi/xlo

    prep_kernel<<<NPTS / 256, 256, 0, stream>>>(x, sq, xhi, xlo);
    knn_kernel<<<NPTS / 64, 1024, 0, stream>>>(x, xhi, xlo, sq, graph);
    xw_kernel<<<NPTS / 64, 384, 0, stream>>>(x, w, w2, XWa, XWb, out);
    pool_kernel<<<NPTS / 8, 256, 0, stream>>>(graph, XWa, XWb, pooled);
    out_kernel<<<NPTS / 64, 256, 0, stream>>>(pooled, w2, out);
}

// Round 7
// 622.464 us; speedup vs baseline: 22.2562x; 1.2616x over previous
//
#include <hip/hip_runtime.h>

// Problem constants
#define NPTS   16384
#define IN_DIM 64
#define HID    128
#define KSEL   32

// Selection parameters (wave-private buffers)
#define CAP    96      // slots per (slice,row); burst proof: TRIG + 16 <= CAP
#define TRIG   80      // compact when n > TRIG
#define WIN_HI 48      // bisect early-exit window
#define SLACK  0.30f   // > 2x worst-case 2-term f16 d2 error (<=0.13 for |x|^2<=130)

typedef _Float16 f16x8 __attribute__((ext_vector_type(8)));
typedef float    f32x4 __attribute__((ext_vector_type(4)));
typedef unsigned short u16;
typedef unsigned int   u32;
typedef unsigned long long u64;

// ---------------------------------------------------------------------------
// Kernel A: prep — fp32 row sqnorm + f16 hi/lo split of x written in PACKED
// MFMA-fragment order: elem[(ct*2+kh)*512 + (g*16+li)*8 + j] = x[ct*16+li][kh*32+g*8+j]
// -> a wave reads a whole fragment as one coalesced 1KB load (lane*16B).
// ---------------------------------------------------------------------------
__global__ __launch_bounds__(256) void prep_kernel(const float* __restrict__ x,
                                                   float* __restrict__ sq,
                                                   u16* __restrict__ ph,
                                                   u16* __restrict__ pl) {
    const int i  = blockIdx.x * 256 + threadIdx.x;   // row
    const int ct = i >> 4, li = i & 15;
    const float4* xr = (const float4*)(x + (size_t)i * IN_DIM);
    float s = 0.f;
#pragma unroll
    for (int c = 0; c < 8; ++c) {                    // c = kh*4+g ; covers k=8c..8c+7
        float4 a = xr[2 * c], b = xr[2 * c + 1];
        float e[8] = {a.x, a.y, a.z, a.w, b.x, b.y, b.z, b.w};
        u32 hw[8], lw[8];
#pragma unroll
        for (int j = 0; j < 8; ++j) {
            s += e[j] * e[j];
            _Float16 h = (_Float16)e[j];
            float hf = (float)h;
            _Float16 l = (_Float16)(e[j] - hf);
            hw[j] = __builtin_bit_cast(u16, h);
            lw[j] = __builtin_bit_cast(u16, l);
        }
        size_t off = ((size_t)ct * 8 + c) * 128 + (size_t)li * 8;
        *(uint4*)(ph + off) = make_uint4(hw[0] | (hw[1] << 16), hw[2] | (hw[3] << 16),
                                         hw[4] | (hw[5] << 16), hw[6] | (hw[7] << 16));
        *(uint4*)(pl + off) = make_uint4(lw[0] | (lw[1] << 16), lw[2] | (lw[3] << 16),
                                         lw[4] | (lw[5] << 16), lw[6] | (lw[7] << 16));
    }
    sq[i] = s;
}

// ---------------------------------------------------------------------------
// Wave-local compaction of one row buffer (no barriers; slice-private).
// ---------------------------------------------------------------------------
__device__ __forceinline__ void compact_row(float* bdrow, u16* bjrow, int* pcnt,
                                            u32* pthr, int lane) {
    int n = *pcnt; n = n < CAP ? n : CAP;
    const float INF = __int_as_float(0x7f800000);
    float dv0 = (lane      < n) ? bdrow[lane]      : INF;
    float dv1 = (lane + 64 < n) ? bdrow[lane + 64] : INF;
    u16   jv0 = (lane      < n) ? bjrow[lane]      : 0;
    u16   jv1 = (lane + 64 < n) ? bjrow[lane + 64] : 0;
    u32 u0 = __float_as_uint(dv0), u1 = __float_as_uint(dv1);
    u32 lo = 0, hi = *pthr, ans = hi;
    for (int it = 0; it < 26 && lo < hi; ++it) {
        u32 mid = lo + ((hi - lo) >> 1);
        int c = __popcll(__ballot(u0 <= mid)) + __popcll(__ballot(u1 <= mid));
        if (c < 32) lo = mid + 1;
        else { hi = mid; ans = mid; if (c <= WIN_HI) break; }
    }
    float ansf = __uint_as_float(ans) + SLACK;       // slack keeps true top-32
    u64 mlt = (1ull << lane) - 1ull;
    bool p0 = dv0 <= ansf;
    u64 b0 = __ballot(p0);
    if (p0) { int p = __popcll(b0 & mlt); bdrow[p] = dv0; bjrow[p] = jv0; }
    int base = __popcll(b0);
    bool p1 = dv1 <= ansf;
    u64 b1 = __ballot(p1);
    if (p1) { int p = base + __popcll(b1 & mlt); if (p < CAP) { bdrow[p] = dv1; bjrow[p] = jv1; } }
    base += __popcll(b1);
    if (lane == 0) {
        *pcnt = base < CAP ? base : CAP;
        atomicMin(pthr, __float_as_uint(ansf));      // shared, monotone
    }
}

// ---------------------------------------------------------------------------
// Kernel B: barrier-free MFMA kNN.
// Grid 1024 blocks (4/CU), block = 256 thr = 4 waves.
// Block owns 16 query rows (rowgroup = blockIdx). Wave w = column-slice w:
// coltiles ct = w + 4*i, i<256. Per coltile: 2 coalesced 1KB fragment loads
// (B-hi only), 4 MFMA f16 (2-term split x 2 k-halves), epilogue filter ->
// wave-private buffer, wave-local compact. ONE __syncthreads, then merge:
// exact fp32 re-verify of <=384 cands/row + bisect-set top-32 (unordered).
// ---------------------------------------------------------------------------
__global__ __launch_bounds__(256, 4) void knn_kernel(const float* __restrict__ x,
                                                     const u16* __restrict__ ph,
                                                     const u16* __restrict__ pl,
                                                     const float* __restrict__ sq,
                                                     int* __restrict__ graph) {
    __shared__ float bd[4][16][CAP];     // 24 KB
    __shared__ u16   bj[4][16][CAP];     // 12 KB
    __shared__ int   bcnt[4][16];
    __shared__ u32   bthrU[16];          // shared across slices (atomicMin)

    const int t = threadIdx.x, lane = t & 63, wave = t >> 6;
    const int g = lane >> 4, li = lane & 15;
    const int rg = blockIdx.x;           // rowgroup: rows rg*16..+15
    const int rbase = rg * 16;

    if (t < 64) bcnt[t >> 4][t & 15] = 0;
    if (t < 16) bthrU[t] = 0x7f800000u;

    // A fragments (hi+lo) for this block's 16 rows, from the packed array.
    f16x8 ah[2], al[2];
#pragma unroll
    for (int kh = 0; kh < 2; ++kh) {
        size_t o = ((size_t)rg * 2 + kh) * 512 + (size_t)lane * 8;
        ah[kh] = *(const f16x8*)(ph + o);
        al[kh] = *(const f16x8*)(pl + o);
    }
    float sar[4];
#pragma unroll
    for (int r = 0; r < 4; ++r) sar[r] = sq[rbase + g * 4 + r];
    __syncthreads();                     // covers bcnt/bthrU init

    // prefetch first coltile
    int ct = wave;
    f16x8 cb0 = *(const f16x8*)(ph + (size_t)ct * 1024 +       (size_t)lane * 8);
    f16x8 cb1 = *(const f16x8*)(ph + (size_t)ct * 1024 + 512 + (size_t)lane * 8);
    float csb = sq[ct * 16 + li];

    for (int i = 0; i < 256; ++i) {
        // prefetch next coltile (no barriers -> overlaps MFMA+epilogue)
        f16x8 nb0, nb1; float nsb = 0.f;
        const int nct = ct + 4;
        if (i < 255) {
            nb0 = *(const f16x8*)(ph + (size_t)nct * 1024 +       (size_t)lane * 8);
            nb1 = *(const f16x8*)(ph + (size_t)nct * 1024 + 512 + (size_t)lane * 8);
            nsb = sq[nct * 16 + li];
        }
        // 2-term split dot: (ah+al).bh  (4 MFMA)
        f32x4 acc = {0.f, 0.f, 0.f, 0.f};
        acc = __builtin_amdgcn_mfma_f32_16x16x32_f16(ah[0], cb0, acc, 0, 0, 0);
        acc = __builtin_amdgcn_mfma_f32_16x16x32_f16(ah[1], cb1, acc, 0, 0, 0);
        acc = __builtin_amdgcn_mfma_f32_16x16x32_f16(al[0], cb0, acc, 0, 0, 0);
        acc = __builtin_amdgcn_mfma_f32_16x16x32_f16(al[1], cb1, acc, 0, 0, 0);

        // epilogue: filter with shared thresholds (stale-read safe: monotone)
        uint4 tu = *(const uint4*)&bthrU[g * 4];
        const float thr[4] = {__uint_as_float(tu.x), __uint_as_float(tu.y),
                              __uint_as_float(tu.z), __uint_as_float(tu.w)};
#pragma unroll
        for (int r = 0; r < 4; ++r) {
            float d = fmaf(-2.f, acc[r], sar[r] + csb);
            if (d <= thr[r]) {
                int row = g * 4 + r;
                int pos = atomicAdd(&bcnt[wave][row], 1);
                if (pos < CAP) {
                    bd[wave][row][pos] = fmaxf(d, 0.f);   // clamp: monotone bits
                    bj[wave][row][pos] = (u16)(ct * 16 + li);
                }
            }
        }
        // wave-local compaction of own slice rows
        u64 need = __ballot((lane < 16) && (bcnt[wave][lane & 15] > TRIG));
        while (need) {
            int rr = __ffsll((long long)need) - 1;
            need &= need - 1;
            compact_row(bd[wave][rr], bj[wave][rr], &bcnt[wave][rr], &bthrU[rr], lane);
        }
        ct = nct; cb0 = nb0; cb1 = nb1; csb = nsb;
    }

    __syncthreads();   // the only cross-wave sync: slices' buffers now final

    // Merge: wave w handles block rows w*4..w*4+3; exact fp32 re-verify of all
    // slices' candidates, then bisect-set top-32 (order-free: pooling is mean).
    const u64 mlt = (1ull << lane) - 1ull;
    for (int ii = 0; ii < 4; ++ii) {
        const int lr = wave * 4 + ii;
        const int gr = rbase + lr;
        const float sqa = sq[gr];
        const float4* xa = (const float4*)(x + (size_t)gr * IN_DIM);
        const int ns0 = min(bcnt[0][lr], CAP), ns1 = min(bcnt[1][lr], CAP);
        const int ns2 = min(bcnt[2][lr], CAP), ns3 = min(bcnt[3][lr], CAP);
        u32 db[6]; int jj[6];
#pragma unroll
        for (int s6 = 0; s6 < 6; ++s6) {
            int f = lane + s6 * 64;            // 0..383
            int sl = f / CAP, idx = f - sl * CAP;
            int nsl = sl == 0 ? ns0 : sl == 1 ? ns1 : sl == 2 ? ns2 : ns3;
            u32 dbits = 0x7f800000u; int j = 0;
            if (idx < nsl) {
                j = bj[sl][lr][idx];
                const float4* xb = (const float4*)(x + (size_t)j * IN_DIM);
                float dot = 0.f;
#pragma unroll
                for (int q = 0; q < 16; ++q) {
                    float4 a = xa[q], b = xb[q];
                    dot += a.x * b.x + a.y * b.y + a.z * b.z + a.w * b.w;
                }
                float d = fmaxf(fmaf(-2.f, dot, sqa + sq[j]), 0.f);
                dbits = __float_as_uint(d);
            }
            db[s6] = dbits; jj[s6] = j;
        }
        // bisect minimal ans with count(<=ans) >= 32 (32 iters = full converge)
        u32 lo = 0, hi = 0x7f800000u, ans = hi;
        for (int it = 0; it < 32 && lo < hi; ++it) {
            u32 mid = lo + ((hi - lo) >> 1);
            int c = 0;
#pragma unroll
            for (int s6 = 0; s6 < 6; ++s6)
                c += __popcll(__ballot(db[s6] <= mid));
            if (c < 32) lo = mid + 1;
            else { hi = mid; ans = mid; if (c == 32) break; }
        }
        // tie handling: keep d<ans plus lowest-index ties to fill 32
        bool tie[6]; int c_lt = 0, c_le = 0;
#pragma unroll
        for (int s6 = 0; s6 < 6; ++s6) {
            tie[s6] = (db[s6] == ans);
            c_lt += __popcll(__ballot(db[s6] < ans));
            c_le += __popcll(__ballot(db[s6] <= ans));
        }
        int extra = (c_le - c_lt) - (32 - c_lt);   // ties beyond need
        while (extra > 0) {                         // rare: drop largest-j ties
            int mx = -1;
#pragma unroll
            for (int s6 = 0; s6 < 6; ++s6) if (tie[s6] && jj[s6] > mx) mx = jj[s6];
#pragma unroll
            for (int off = 32; off > 0; off >>= 1) {
                int o = __shfl_xor(mx, off); mx = mx > o ? mx : o;
            }
#pragma unroll
            for (int s6 = 0; s6 < 6; ++s6) if (tie[s6] && jj[s6] == mx) tie[s6] = false;
            --extra;
        }
        int* gp = graph + (size_t)gr * KSEL;
        int base = 0;
#pragma unroll
        for (int s6 = 0; s6 < 6; ++s6) {
            bool k = (db[s6] < ans) || tie[s6];
            u64 b = __ballot(k);
            if (k) gp[base + __popcll(b & mlt)] = jj[s6];
            base += __popcll(b);
        }
    }
}

// ---------------------------------------------------------------------------
// Kernel C: XWa[i][h]=x_i.w[h][0:64], XWb[i][h]=x_i.w[h][64:128],
//           OUTB[i][o]=x_i.w2[o][128:192] (direct to d_out).
// ---------------------------------------------------------------------------
__global__ __launch_bounds__(384) void xw_kernel(const float* __restrict__ x,
                                                 const float* __restrict__ w,
                                                 const float* __restrict__ w2,
                                                 float* __restrict__ XWa,
                                                 float* __restrict__ XWb,
                                                 float* __restrict__ outb) {
    __shared__ float xs[64][64];
    const int t = threadIdx.x;
    const int rbase = blockIdx.x * 64;

    for (int idx = t; idx < 64 * 16; idx += 384) {
        int r = idx >> 4, q = idx & 15;
        ((float4*)xs[r])[q] = ((const float4*)(x + (size_t)(rbase + r) * IN_DIM))[q];
    }
    const int kind = t >> 7;
    const int idx  = t & 127;
    const float* wp = (kind == 0) ? (w + (size_t)idx * 128)
                    : (kind == 1) ? (w + (size_t)idx * 128 + 64)
                                  : (w2 + (size_t)idx * 192 + 128);
    float4 wreg[16];
#pragma unroll
    for (int q = 0; q < 16; ++q) wreg[q] = ((const float4*)wp)[q];
    __syncthreads();

    for (int r = 0; r < 64; ++r) {
        float acc = 0.f;
#pragma unroll
        for (int q = 0; q < 16; ++q) {
            float4 xv = ((float4*)xs[r])[q];
            acc += xv.x * wreg[q].x + xv.y * wreg[q].y +
                   xv.z * wreg[q].z + xv.w * wreg[q].w;
        }
        size_t o = (size_t)(rbase + r) * 128 + idx;
        if (kind == 0)      XWa[o]  = acc;
        else if (kind == 1) XWb[o]  = acc;
        else                outb[o] = acc;
    }
}

// ---------------------------------------------------------------------------
// Kernel D: pooled[i][h] = mean_c clip(XWa[g[i][c]][h] + XWb[i][h], -1, 1)
// One wave per row: shfl-broadcast neighbor index -> coalesced 512B gathers.
// ---------------------------------------------------------------------------
__global__ __launch_bounds__(256) void pool_kernel(const int* __restrict__ graph,
                                                   const float* __restrict__ XWa,
                                                   const float* __restrict__ XWb,
                                                   float* __restrict__ pooled) {
    const int t = threadIdx.x, lane = t & 63, wave = t >> 6;
    const int row = blockIdx.x * 4 + wave;
    int gi = graph[(size_t)row * KSEL + (lane & 31)];
    float2 b = ((const float2*)(XWb + (size_t)row * HID))[lane];
    float2 acc = {0.f, 0.f};
#pragma unroll
    for (int c = 0; c < KSEL; ++c) {
        int j = __shfl(gi, c);
        float2 v = ((const float2*)(XWa + (size_t)j * HID))[lane];
        acc.x += fminf(fmaxf(v.x + b.x, -1.f), 1.f);
        acc.y += fminf(fmaxf(v.y + b.y, -1.f), 1.f);
    }
    float2* pr = (float2*)(pooled + (size_t)row * HID);
    pr[lane] = make_float2(acc.x * (1.f / 32.f), acc.y * (1.f / 32.f));
}

// ---------------------------------------------------------------------------
// Kernel E: out[i][o] += pooled[i] . w2[o][0:128]  (out holds OUTB)
// ---------------------------------------------------------------------------
__global__ __launch_bounds__(256) void out_kernel(const float* __restrict__ pooled,
                                                  const float* __restrict__ w2,
                                                  float* __restrict__ out) {
    __shared__ float ws2[128][132];
    __shared__ float pt[64][128];
    const int t = threadIdx.x;
    const int rbase = blockIdx.x * 64;

    for (int idx = t; idx < 128 * 32; idx += 256) {
        int o = idx >> 5, q = idx & 31;
        ((float4*)&ws2[o][0])[q] = ((const float4*)(w2 + (size_t)o * 192))[q];
    }
    for (int idx = t; idx < 64 * 32; idx += 256) {
        int r = idx >> 5, q = idx & 31;
        ((float4*)&pt[r][0])[q] = ((const float4*)(pooled + (size_t)(rbase + r) * 128))[q];
    }
    __syncthreads();

    const int o = t & 127, rsub = t >> 7;
    for (int rp = 0; rp < 32; ++rp) {
        int r = rp * 2 + rsub;
        float acc = 0.f;
#pragma unroll
        for (int q = 0; q < 32; ++q) {
            float4 pv = ((float4*)&pt[r][0])[q];
            float4 wv = ((float4*)&ws2[o][0])[q];
            acc += pv.x * wv.x + pv.y * wv.y + pv.z * wv.z + pv.w * wv.w;
        }
        size_t off = (size_t)(rbase + r) * 128 + o;
        out[off] += acc;
    }
}

// ---------------------------------------------------------------------------
extern "C" void kernel_launch(void* const* d_in, const int* in_sizes, int n_in,
                              void* d_out, int out_size, void* d_ws, size_t ws_size,
                              hipStream_t stream) {
    const float* x  = (const float*)d_in[0];   // (16384, 64)
    const float* w  = (const float*)d_in[1];   // (128, 128)
    const float* w2 = (const float*)d_in[2];   // (128, 192)
    float* out = (float*)d_out;                // (16384, 128)

    // workspace (26.07 MB): pooled aliases ph/pl (pool runs after knn)
    float* sq     = (float*)d_ws;                           // 64 KB
    int*   graph  = (int*)(sq + NPTS);                      // 2 MB
    float* XWa    = (float*)(graph + (size_t)NPTS * KSEL);  // 8 MB
    float* XWb    = XWa + (size_t)NPTS * HID;               // 8 MB
    float* region = XWb + (size_t)NPTS * HID;               // 8 MB
    u16*   ph     = (u16*)region;                           // 2 MB (packed f16 hi)
    u16*   pl     = ph + (size_t)NPTS * IN_DIM;             // 2 MB (packed f16 lo)
    float* pooled = region;                                 // aliases ph/pl

    prep_kernel<<<NPTS / 256, 256, 0, stream>>>(x, sq, ph, pl);
    knn_kernel<<<NPTS / 16, 256, 0, stream>>>(x, ph, pl, sq, graph);
    xw_kernel<<<NPTS / 64, 384, 0, stream>>>(x, w, w2, XWa, XWb, out);
    pool_kernel<<<NPTS / 4, 256, 0, stream>>>(graph, XWa, XWb, pooled);
    out_kernel<<<NPTS / 64, 256, 0, stream>>>(pooled, w2, out);
}